// Round 6
// baseline (514.113 us; speedup 1.0000x reference)
//
#include <hip/hip_runtime.h>
#include <hip/hip_bf16.h>

constexpr int B = 8, C = 128, H = 80, W = 80, O = 128;
constexpr int HW = H * W;              // 6400
constexpr int NPIX = B * HW;           // 51200
constexpr int KC = C * 9;              // 1152
constexpr int PX = 32;                 // pixels per block (dcn/offc kernels)

typedef __attribute__((ext_vector_type(8))) short short8;
typedef __attribute__((ext_vector_type(4))) float f32x4;

__device__ inline ushort f2b(float f) {  // fp32 -> bf16 bits, RNE
  uint u = __float_as_uint(f);
  return (ushort)((u + 0x7FFFu + ((u >> 16) & 1u)) >> 16);
}
__device__ inline void unp(uint u, float& lo, float& hi) {  // packed bf16 -> fp32
  lo = __uint_as_float(u << 16);
  hi = __uint_as_float(u & 0xFFFF0000u);
}
__device__ inline uint pk2(float lo, float hi) {  // 2 f32 -> packed bf16 (RNE)
  __hip_bfloat162 h = __float22bfloat162_rn(make_float2(lo, hi));
  return *reinterpret_cast<uint*>(&h);
}
// ushort index into a [px][256B] LDS buffer, T2 XOR-swizzled (involution).
__device__ inline int swz16(int px, int byte) {
  return (px * 256 + (byte ^ ((px & 7) << 4))) >> 1;
}

// ------- kernel 0a: x [B][C][HW] fp32 -> xt [B][HW][C] bf16 -----------------
__global__ __launch_bounds__(256) void k_xt(const float* __restrict__ x,
                                            ushort* __restrict__ xt) {
  const int t = threadIdx.x;
  const int g = t >> 4;            // channel chunk: c = 8g..8g+7
  const int hl = t & 15;
  const int p0 = blockIdx.x * 16;
  const int b = p0 / HW, hw = p0 - b * HW + hl;
  const float* xb = x + (size_t)b * C * HW + hw;
  uint u[4];
#pragma unroll
  for (int i = 0; i < 4; ++i) {
    float lo = xb[(size_t)(g * 8 + 2 * i) * HW];
    float hi = xb[(size_t)(g * 8 + 2 * i + 1) * HW];
    u[i] = (uint)f2b(lo) | ((uint)f2b(hi) << 16);
  }
  *(uint4*)(xt + ((size_t)b * HW + hw) * C + g * 8) = make_uint4(u[0], u[1], u[2], u[3]);
}

// ------- kernel 0b: weight transforms, k-major bf16; zero part & zrow -------
__global__ __launch_bounds__(256) void k_wt2(const float* __restrict__ w_dcn,
                                             const float* __restrict__ w_off,
                                             ushort* __restrict__ wt,
                                             ushort* __restrict__ wof,
                                             float* __restrict__ part,
                                             ushort* __restrict__ zrow) {
  int i = blockIdx.x * 256 + threadIdx.x;
  if (i < O * KC) {
    int c = i & 127, k = (i >> 7) % 9, o = i / KC;
    wt[i] = f2b(w_dcn[(size_t)o * KC + c * 9 + k]);
  }
  if (i < 32 * KC) {
    int c = i & 127, k = (i >> 7) % 9, o = i / KC;
    wof[i] = (o < 27) ? f2b(w_off[((size_t)o * C + c) * 9 + k]) : (ushort)0;
  }
  if (i < 256) part[i] = 0.0f;
  if (i < 128) zrow[i] = 0;
}

// ------- kernel 1: offset conv via MFMA, NO LDS (B read direct from L2) -----
// 256 thr = 4 waves; wave wv -> (mi = wv&1, nt = wv>>1); 32 px/block.
__global__ __launch_bounds__(256, 6) void k_offc4(
    const ushort* __restrict__ xt, const ushort* __restrict__ wof,
    const ushort* __restrict__ zrow, const float* __restrict__ b_off,
    float* __restrict__ om) {
  const int t = threadIdx.x;
  const int bid = (blockIdx.x & 7) * 200 + (blockIdx.x >> 3);  // XCD chunking
  const int b = bid / 200, hw0 = (bid - b * 200) * PX;
  const int lane = t & 63, wv = t >> 6, rl = lane & 15, gh = lane >> 4;
  const int mi = wv & 1, nt = wv >> 1;
  const int px = hw0 + nt * 16 + rl;
  const int hp = px / W, wp = px - hp * W;
  const ushort* xb = xt + (size_t)b * HW * C;
  f32x4 acc = {0.f, 0.f, 0.f, 0.f};
#pragma unroll
  for (int k = 0; k < 9; ++k) {
    int ky = k / 3, kx = k - ky * 3;
    int y = hp + ky - 1, xx = wp + kx - 1;
    bool ok = ((unsigned)y < (unsigned)H) && ((unsigned)xx < (unsigned)W);
    const ushort* rowp = ok ? (xb + (size_t)(y * W + xx) * C) : zrow;
    const ushort* aP = wof + (size_t)(mi * 16 + rl) * KC + k * 128 + gh * 8;
#pragma unroll
    for (int kk = 0; kk < 4; ++kk) {
      short8 av = *(const short8*)(aP + kk * 32);
      short8 bv = *(const short8*)(rowp + kk * 32 + gh * 8);
      acc = __builtin_amdgcn_mfma_f32_16x16x32_bf16(av, bv, acc, 0, 0, 0);
    }
  }
  float* ob = om + (size_t)b * 27 * HW + hw0 + nt * 16 + rl;
#pragma unroll
  for (int r = 0; r < 4; ++r) {
    int oc = mi * 16 + gh * 4 + r;
    if (oc < 27) ob[(size_t)oc * HW] = acc[r] + b_off[oc];
  }
}

// ------- kernel 2: bilinear gather + MFMA GEMM, asm-pinned prefetch ---------
// 256 thr = 4 waves, 32 px/block, all O=128. Wave: 2 m-tiles x 2 n-tiles.
__global__ __launch_bounds__(256, 4) void k_dcn3(
    const ushort* __restrict__ xt, const float* __restrict__ om,
    const ushort* __restrict__ wt, float* __restrict__ outr,
    float* __restrict__ part) {
  __shared__ float s_w[PX][9][4];
  __shared__ int s_i[PX][9][4];
  __shared__ __align__(16) ushort s_buf[2][PX * 128];
  const int t = threadIdx.x;
  const int bid = (blockIdx.x & 7) * 200 + (blockIdx.x >> 3);  // XCD chunking
  const int b = bid / 200, hw0 = (bid - b * 200) * PX;

  // metadata: 32 px x 9 taps (mask folded into corner weights)
  for (int idx = t; idx < PX * 9; idx += 256) {
    int px = idx / 9, k = idx - (idx / 9) * 9;
    int hw = hw0 + px, h = hw / W, w = hw - (hw / W) * W;
    int ky = k / 3, kx = k - ky * 3;
    const float* omp = om + (size_t)b * 27 * HW + hw;
    float dy = omp[(size_t)(2 * k) * HW];
    float dx = omp[(size_t)(2 * k + 1) * HW];
    float mk = 1.0f / (1.0f + __expf(-omp[(size_t)(18 + k) * HW]));
    float py = dy + (float)(h - 1 + ky);
    float pxf = dx + (float)(w - 1 + kx);
    float y0f = floorf(py), x0f = floorf(pxf);
    float wy1 = py - y0f, wx1 = pxf - x0f;
    float wy0 = 1.0f - wy1, wx0 = 1.0f - wx1;
    int y0 = (int)y0f, x0 = (int)x0f;
    int y1 = y0 + 1, x1 = x0 + 1;
    bool vy0 = (y0 >= 0) && (y0 < H);
    bool vy1 = (y1 >= 0) && (y1 < H);
    bool vx0 = (x0 >= 0) && (x0 < W);
    bool vx1 = (x1 >= 0) && (x1 < W);
    int cy0 = min(max(y0, 0), H - 1), cy1 = min(max(y1, 0), H - 1);
    int cx0 = min(max(x0, 0), W - 1), cx1 = min(max(x1, 0), W - 1);
    s_w[px][k][0] = (vy0 && vx0) ? wy0 * wx0 * mk : 0.0f;
    s_w[px][k][1] = (vy0 && vx1) ? wy0 * wx1 * mk : 0.0f;
    s_w[px][k][2] = (vy1 && vx0) ? wy1 * wx0 * mk : 0.0f;
    s_w[px][k][3] = (vy1 && vx1) ? wy1 * wx1 * mk : 0.0f;
    s_i[px][k][0] = cy0 * W + cx0;
    s_i[px][k][1] = cy0 * W + cx1;
    s_i[px][k][2] = cy1 * W + cx0;
    s_i[px][k][3] = cy1 * W + cx1;
  }
  __syncthreads();

  // staging role: sp = pixel, sq = 32B channel chunk (16 ch)
  const int sp = t >> 3, sq = t & 7;
  const ushort* xbq = xt + (size_t)b * HW * C + sq * 16;
  uint4 lA0, lA1, lB0, lB1, lC0, lC1, lD0, lD1;   // pinned prefetch (32 VGPR)
  float cw0, cw1, cw2, cw3;

  auto SLOAD = [&](int k) {
    int4 ii = *(const int4*)&s_i[sp][k][0];
    float4 wf = *(const float4*)&s_w[sp][k][0];
    cw0 = wf.x; cw1 = wf.y; cw2 = wf.z; cw3 = wf.w;
    const ushort* r0 = xbq + (size_t)ii.x * C;
    const ushort* r1 = xbq + (size_t)ii.y * C;
    const ushort* r2 = xbq + (size_t)ii.z * C;
    const ushort* r3 = xbq + (size_t)ii.w * C;
    // volatile asm: loads issue HERE and cannot be sunk past COMP.
    asm volatile("global_load_dwordx4 %0, %2, off\n\t"
                 "global_load_dwordx4 %1, %2, off offset:16"
                 : "=&v"(lA0), "=&v"(lA1) : "v"(r0));
    asm volatile("global_load_dwordx4 %0, %2, off\n\t"
                 "global_load_dwordx4 %1, %2, off offset:16"
                 : "=&v"(lB0), "=&v"(lB1) : "v"(r1));
    asm volatile("global_load_dwordx4 %0, %2, off\n\t"
                 "global_load_dwordx4 %1, %2, off offset:16"
                 : "=&v"(lC0), "=&v"(lC1) : "v"(r2));
    asm volatile("global_load_dwordx4 %0, %2, off\n\t"
                 "global_load_dwordx4 %1, %2, off offset:16"
                 : "=&v"(lD0), "=&v"(lD1) : "v"(r3));
  };

  auto SWRITE = [&](ushort* buf) {
    uint qa[8] = {lA0.x, lA0.y, lA0.z, lA0.w, lA1.x, lA1.y, lA1.z, lA1.w};
    uint qb[8] = {lB0.x, lB0.y, lB0.z, lB0.w, lB1.x, lB1.y, lB1.z, lB1.w};
    uint qc[8] = {lC0.x, lC0.y, lC0.z, lC0.w, lC1.x, lC1.y, lC1.z, lC1.w};
    uint qd[8] = {lD0.x, lD0.y, lD0.z, lD0.w, lD1.x, lD1.y, lD1.z, lD1.w};
    uint r[8];
#pragma unroll
    for (int d = 0; d < 8; ++d) {
      float a0, a1, b0, b1, c0, c1, d0, d1;
      unp(qa[d], a0, a1);
      unp(qb[d], b0, b1);
      unp(qc[d], c0, c1);
      unp(qd[d], d0, d1);
      float vlo = fmaf(cw3, d0, fmaf(cw2, c0, fmaf(cw1, b0, cw0 * a0)));
      float vhi = fmaf(cw3, d1, fmaf(cw2, c1, fmaf(cw1, b1, cw0 * a1)));
      r[d] = pk2(vlo, vhi);
    }
    *(uint4*)(buf + swz16(sp, sq * 32)) = make_uint4(r[0], r[1], r[2], r[3]);
    *(uint4*)(buf + swz16(sp, sq * 32 + 16)) = make_uint4(r[4], r[5], r[6], r[7]);
  };

  const int lane = t & 63, wv = t >> 6, rl = lane & 15, gh = lane >> 4;
  f32x4 acc00 = {0.f, 0.f, 0.f, 0.f}, acc01 = acc00, acc10 = acc00, acc11 = acc00;

  auto COMP = [&](const ushort* buf, int k) {
    const ushort* aP = wt + (size_t)(wv * 32 + rl) * KC + k * 128 + gh * 8;
    __builtin_amdgcn_s_setprio(1);
#pragma unroll
    for (int kk = 0; kk < 4; ++kk) {
      short8 av0 = *(const short8*)(aP + kk * 32);
      short8 av1 = *(const short8*)(aP + (size_t)16 * KC + kk * 32);
      short8 bv0 = *(const short8*)(buf + swz16(rl, kk * 64 + gh * 16));
      short8 bv1 = *(const short8*)(buf + swz16(16 + rl, kk * 64 + gh * 16));
      acc00 = __builtin_amdgcn_mfma_f32_16x16x32_bf16(av0, bv0, acc00, 0, 0, 0);
      acc01 = __builtin_amdgcn_mfma_f32_16x16x32_bf16(av0, bv1, acc01, 0, 0, 0);
      acc10 = __builtin_amdgcn_mfma_f32_16x16x32_bf16(av1, bv0, acc10, 0, 0, 0);
      acc11 = __builtin_amdgcn_mfma_f32_16x16x32_bf16(av1, bv1, acc11, 0, 0, 0);
    }
    __builtin_amdgcn_s_setprio(0);
  };

  SLOAD(0);
  asm volatile("s_waitcnt vmcnt(0)" ::: "memory");
  __builtin_amdgcn_sched_barrier(0);
  SWRITE(s_buf[0]);
  __syncthreads();
  for (int k = 0; k < 9; ++k) {
    if (k < 8) SLOAD(k + 1);
    COMP(s_buf[k & 1], k);
    __builtin_amdgcn_sched_barrier(0);
    if (k < 8) {
      asm volatile("s_waitcnt vmcnt(0)" ::: "memory");
      __builtin_amdgcn_sched_barrier(0);
      SWRITE(s_buf[(k + 1) & 1]);
      __syncthreads();
    }
  }

  // C-write + fused BN partial sums (atomic, part pre-zeroed by k_wt2)
  float* outb = outr + (size_t)b * O * HW + hw0 + rl;
#pragma unroll
  for (int mi = 0; mi < 2; ++mi) {
    f32x4 a0 = mi ? acc10 : acc00;
    f32x4 a1 = mi ? acc11 : acc01;
#pragma unroll
    for (int r = 0; r < 4; ++r) {
      int o = wv * 32 + mi * 16 + gh * 4 + r;
      outb[(size_t)o * HW] = a0[r];
      outb[(size_t)o * HW + 16] = a1[r];
      float s = a0[r] + a1[r];
      float s2 = fmaf(a0[r], a0[r], a1[r] * a1[r]);
#pragma unroll
      for (int m = 1; m < 16; m <<= 1) {
        s += __shfl_xor(s, m);
        s2 += __shfl_xor(s2, m);
      }
      if (rl == 0) {
        atomicAdd(&part[2 * o], s);
        atomicAdd(&part[2 * o + 1], s2);
      }
    }
  }
}

// ------- kernel 3: BN finalize + affine + SiLU, in place on d_out -----------
__global__ __launch_bounds__(256) void k_bnapply2(
    float* __restrict__ outr, const float* __restrict__ part,
    const float* __restrict__ gamma, const float* __restrict__ beta) {
  const int n4 = B * O * HW / 4;
  for (int i = blockIdx.x * blockDim.x + threadIdx.x; i < n4;
       i += gridDim.x * blockDim.x) {
    int o = (i / (HW / 4)) % O;
    float S = part[2 * o], S2 = part[2 * o + 1];
    const float inv = 1.0f / (float)(B * HW);
    float mu = S * inv;
    float rstd = rsqrtf(fmaf(S2, inv, -mu * mu) + 1e-5f);
    float a = rstd * gamma[o];
    float bb = fmaf(-mu, a, beta[o]);
    float4 v = ((const float4*)outr)[i];
    float y0 = fmaf(v.x, a, bb);
    float y1 = fmaf(v.y, a, bb);
    float y2 = fmaf(v.z, a, bb);
    float y3 = fmaf(v.w, a, bb);
    v.x = y0 / (1.0f + __expf(-y0));
    v.y = y1 / (1.0f + __expf(-y1));
    v.z = y2 / (1.0f + __expf(-y2));
    v.w = y3 / (1.0f + __expf(-y3));
    ((float4*)outr)[i] = v;
  }
}

extern "C" void kernel_launch(void* const* d_in, const int* in_sizes, int n_in,
                              void* d_out, int out_size, void* d_ws, size_t ws_size,
                              hipStream_t stream) {
  const float* x = (const float*)d_in[0];
  const float* w_dcn = (const float*)d_in[1];
  // d_in[2] = b_dcn: per-channel constant, exactly cancelled by BN mean-sub.
  const float* w_off = (const float*)d_in[3];
  const float* b_off = (const float*)d_in[4];
  const float* gamma = (const float*)d_in[5];
  const float* beta = (const float*)d_in[6];
  float* out = (float*)d_out;
  // ws: om 5.53MB | xt 13.1MB | wt 288KB | wof 72KB | part 1KB | zrow 256B
  float* om = (float*)d_ws;
  ushort* xt = (ushort*)(om + (size_t)B * 27 * HW);
  ushort* wt = xt + (size_t)B * HW * C;
  ushort* wof = wt + (size_t)O * KC;
  float* part = (float*)(wof + (size_t)32 * KC);
  ushort* zrow = (ushort*)(part + 256);

  k_xt<<<NPIX / 16, 256, 0, stream>>>(x, xt);
  k_wt2<<<(O * KC + 255) / 256, 256, 0, stream>>>(w_dcn, w_off, wt, wof, part, zrow);
  k_offc4<<<NPIX / PX, 256, 0, stream>>>(xt, wof, zrow, b_off, om);
  k_dcn3<<<NPIX / PX, 256, 0, stream>>>(xt, om, wt, out, part);
  k_bnapply2<<<2048, 256, 0, stream>>>(out, part, gamma, beta);
}

// Round 7
// 245.315 us; speedup vs baseline: 2.0957x; 2.0957x over previous
//
#include <hip/hip_runtime.h>
#include <hip/hip_bf16.h>

constexpr int B = 8, C = 128, H = 80, W = 80, O = 128;
constexpr int HW = H * W;              // 6400
constexpr int NPIX = B * HW;           // 51200
constexpr int KC = C * 9;              // 1152
constexpr int PX = 32;                 // pixels per block (dcn/offc kernels)
constexpr int NBLK = NPIX / PX;        // 1600

typedef __attribute__((ext_vector_type(8))) short short8;
typedef __attribute__((ext_vector_type(4))) float f32x4;

__device__ inline ushort f2b(float f) {  // fp32 -> bf16 bits, RNE
  uint u = __float_as_uint(f);
  return (ushort)((u + 0x7FFFu + ((u >> 16) & 1u)) >> 16);
}
__device__ inline void unp(uint u, float& lo, float& hi) {  // packed bf16 -> fp32
  lo = __uint_as_float(u << 16);
  hi = __uint_as_float(u & 0xFFFF0000u);
}
__device__ inline uint pk2(float lo, float hi) {  // 2 f32 -> packed bf16 (RNE)
  __hip_bfloat162 h = __float22bfloat162_rn(make_float2(lo, hi));
  return *reinterpret_cast<uint*>(&h);
}
// ushort index into a [px][256B] LDS buffer, T2 XOR-swizzled (involution).
__device__ inline int swz16(int px, int byte) {
  return (px * 256 + (byte ^ ((px & 7) << 4))) >> 1;
}

// ------- kernel 0a: x [B][C][HW] fp32 -> xt [B][HW][C] bf16 -----------------
__global__ __launch_bounds__(256) void k_xt(const float* __restrict__ x,
                                            ushort* __restrict__ xt) {
  const int t = threadIdx.x;
  const int g = t >> 4;            // channel chunk: c = 8g..8g+7
  const int hl = t & 15;
  const int p0 = blockIdx.x * 16;
  const int b = p0 / HW, hw = p0 - b * HW + hl;
  const float* xb = x + (size_t)b * C * HW + hw;
  uint u[4];
#pragma unroll
  for (int i = 0; i < 4; ++i) {
    float lo = xb[(size_t)(g * 8 + 2 * i) * HW];
    float hi = xb[(size_t)(g * 8 + 2 * i + 1) * HW];
    u[i] = (uint)f2b(lo) | ((uint)f2b(hi) << 16);
  }
  *(uint4*)(xt + ((size_t)b * HW + hw) * C + g * 8) = make_uint4(u[0], u[1], u[2], u[3]);
}

// ------- kernel 0b: weight transforms, k-major bf16; zero zrow --------------
__global__ __launch_bounds__(256) void k_wt2(const float* __restrict__ w_dcn,
                                             const float* __restrict__ w_off,
                                             ushort* __restrict__ wt,
                                             ushort* __restrict__ wof,
                                             ushort* __restrict__ zrow) {
  int i = blockIdx.x * 256 + threadIdx.x;
  if (i < O * KC) {
    int c = i & 127, k = (i >> 7) % 9, o = i / KC;
    wt[i] = f2b(w_dcn[(size_t)o * KC + c * 9 + k]);
  }
  if (i < 32 * KC) {
    int c = i & 127, k = (i >> 7) % 9, o = i / KC;
    wof[i] = (o < 27) ? f2b(w_off[((size_t)o * C + c) * 9 + k]) : (ushort)0;
  }
  if (i < 128) zrow[i] = 0;
}

// ------- kernel 1: offset conv via MFMA, NO LDS (B read direct from L2) -----
// 256 thr = 4 waves; wave wv -> (mi = wv&1, nt = wv>>1); 32 px/block.
__global__ __launch_bounds__(256, 6) void k_offc4(
    const ushort* __restrict__ xt, const ushort* __restrict__ wof,
    const ushort* __restrict__ zrow, const float* __restrict__ b_off,
    float* __restrict__ om) {
  const int t = threadIdx.x;
  const int bid = (blockIdx.x & 7) * 200 + (blockIdx.x >> 3);  // XCD chunking
  const int b = bid / 200, hw0 = (bid - b * 200) * PX;
  const int lane = t & 63, wv = t >> 6, rl = lane & 15, gh = lane >> 4;
  const int mi = wv & 1, nt = wv >> 1;
  const int px = hw0 + nt * 16 + rl;
  const int hp = px / W, wp = px - hp * W;
  const ushort* xb = xt + (size_t)b * HW * C;
  f32x4 acc = {0.f, 0.f, 0.f, 0.f};
#pragma unroll
  for (int k = 0; k < 9; ++k) {
    int ky = k / 3, kx = k - ky * 3;
    int y = hp + ky - 1, xx = wp + kx - 1;
    bool ok = ((unsigned)y < (unsigned)H) && ((unsigned)xx < (unsigned)W);
    const ushort* rowp = ok ? (xb + (size_t)(y * W + xx) * C) : zrow;
    const ushort* aP = wof + (size_t)(mi * 16 + rl) * KC + k * 128 + gh * 8;
#pragma unroll
    for (int kk = 0; kk < 4; ++kk) {
      short8 av = *(const short8*)(aP + kk * 32);
      short8 bv = *(const short8*)(rowp + kk * 32 + gh * 8);
      acc = __builtin_amdgcn_mfma_f32_16x16x32_bf16(av, bv, acc, 0, 0, 0);
    }
  }
  float* ob = om + (size_t)b * 27 * HW + hw0 + nt * 16 + rl;
#pragma unroll
  for (int r = 0; r < 4; ++r) {
    int oc = mi * 16 + gh * 4 + r;
    if (oc < 27) ob[(size_t)oc * HW] = acc[r] + b_off[oc];
  }
}

// ------- kernel 2: bilinear gather + MFMA GEMM, asm-pinned prefetch ---------
// 256 thr = 4 waves, 32 px/block, all O=128. Wave: 2 m-tiles x 2 n-tiles.
__global__ __launch_bounds__(256, 4) void k_dcn3(
    const ushort* __restrict__ xt, const float* __restrict__ om,
    const ushort* __restrict__ wt, float* __restrict__ outr,
    float* __restrict__ part2) {
  __shared__ float s_w[PX][9][4];
  __shared__ int s_i[PX][9][4];
  __shared__ __align__(16) ushort s_buf[2][PX * 128];
  const int t = threadIdx.x;
  const int bid = (blockIdx.x & 7) * 200 + (blockIdx.x >> 3);  // XCD chunking
  const int b = bid / 200, hw0 = (bid - b * 200) * PX;

  // metadata: 32 px x 9 taps (mask folded into corner weights)
  for (int idx = t; idx < PX * 9; idx += 256) {
    int px = idx / 9, k = idx - (idx / 9) * 9;
    int hw = hw0 + px, h = hw / W, w = hw - (hw / W) * W;
    int ky = k / 3, kx = k - ky * 3;
    const float* omp = om + (size_t)b * 27 * HW + hw;
    float dy = omp[(size_t)(2 * k) * HW];
    float dx = omp[(size_t)(2 * k + 1) * HW];
    float mk = 1.0f / (1.0f + __expf(-omp[(size_t)(18 + k) * HW]));
    float py = dy + (float)(h - 1 + ky);
    float pxf = dx + (float)(w - 1 + kx);
    float y0f = floorf(py), x0f = floorf(pxf);
    float wy1 = py - y0f, wx1 = pxf - x0f;
    float wy0 = 1.0f - wy1, wx0 = 1.0f - wx1;
    int y0 = (int)y0f, x0 = (int)x0f;
    int y1 = y0 + 1, x1 = x0 + 1;
    bool vy0 = (y0 >= 0) && (y0 < H);
    bool vy1 = (y1 >= 0) && (y1 < H);
    bool vx0 = (x0 >= 0) && (x0 < W);
    bool vx1 = (x1 >= 0) && (x1 < W);
    int cy0 = min(max(y0, 0), H - 1), cy1 = min(max(y1, 0), H - 1);
    int cx0 = min(max(x0, 0), W - 1), cx1 = min(max(x1, 0), W - 1);
    s_w[px][k][0] = (vy0 && vx0) ? wy0 * wx0 * mk : 0.0f;
    s_w[px][k][1] = (vy0 && vx1) ? wy0 * wx1 * mk : 0.0f;
    s_w[px][k][2] = (vy1 && vx0) ? wy1 * wx0 * mk : 0.0f;
    s_w[px][k][3] = (vy1 && vx1) ? wy1 * wx1 * mk : 0.0f;
    s_i[px][k][0] = cy0 * W + cx0;
    s_i[px][k][1] = cy0 * W + cx1;
    s_i[px][k][2] = cy1 * W + cx0;
    s_i[px][k][3] = cy1 * W + cx1;
  }
  __syncthreads();

  // staging role: sp = pixel, sq = 32B channel chunk (16 ch)
  const int sp = t >> 3, sq = t & 7;
  const ushort* xbq = xt + (size_t)b * HW * C + sq * 16;
  uint4 lA0, lA1, lB0, lB1, lC0, lC1, lD0, lD1;   // pinned prefetch (32 VGPR)
  float cw0, cw1, cw2, cw3;

  auto SLOAD = [&](int k) {
    int4 ii = *(const int4*)&s_i[sp][k][0];
    float4 wf = *(const float4*)&s_w[sp][k][0];
    cw0 = wf.x; cw1 = wf.y; cw2 = wf.z; cw3 = wf.w;
    const ushort* r0 = xbq + (size_t)ii.x * C;
    const ushort* r1 = xbq + (size_t)ii.y * C;
    const ushort* r2 = xbq + (size_t)ii.z * C;
    const ushort* r3 = xbq + (size_t)ii.w * C;
    // volatile asm: loads issue HERE and cannot be sunk past COMP.
    asm volatile("global_load_dwordx4 %0, %2, off\n\t"
                 "global_load_dwordx4 %1, %2, off offset:16"
                 : "=&v"(lA0), "=&v"(lA1) : "v"(r0));
    asm volatile("global_load_dwordx4 %0, %2, off\n\t"
                 "global_load_dwordx4 %1, %2, off offset:16"
                 : "=&v"(lB0), "=&v"(lB1) : "v"(r1));
    asm volatile("global_load_dwordx4 %0, %2, off\n\t"
                 "global_load_dwordx4 %1, %2, off offset:16"
                 : "=&v"(lC0), "=&v"(lC1) : "v"(r2));
    asm volatile("global_load_dwordx4 %0, %2, off\n\t"
                 "global_load_dwordx4 %1, %2, off offset:16"
                 : "=&v"(lD0), "=&v"(lD1) : "v"(r3));
  };

  auto SWRITE = [&](ushort* buf) {
    uint qa[8] = {lA0.x, lA0.y, lA0.z, lA0.w, lA1.x, lA1.y, lA1.z, lA1.w};
    uint qb[8] = {lB0.x, lB0.y, lB0.z, lB0.w, lB1.x, lB1.y, lB1.z, lB1.w};
    uint qc[8] = {lC0.x, lC0.y, lC0.z, lC0.w, lC1.x, lC1.y, lC1.z, lC1.w};
    uint qd[8] = {lD0.x, lD0.y, lD0.z, lD0.w, lD1.x, lD1.y, lD1.z, lD1.w};
    uint r[8];
#pragma unroll
    for (int d = 0; d < 8; ++d) {
      float a0, a1, b0, b1, c0, c1, d0, d1;
      unp(qa[d], a0, a1);
      unp(qb[d], b0, b1);
      unp(qc[d], c0, c1);
      unp(qd[d], d0, d1);
      float vlo = fmaf(cw3, d0, fmaf(cw2, c0, fmaf(cw1, b0, cw0 * a0)));
      float vhi = fmaf(cw3, d1, fmaf(cw2, c1, fmaf(cw1, b1, cw0 * a1)));
      r[d] = pk2(vlo, vhi);
    }
    *(uint4*)(buf + swz16(sp, sq * 32)) = make_uint4(r[0], r[1], r[2], r[3]);
    *(uint4*)(buf + swz16(sp, sq * 32 + 16)) = make_uint4(r[4], r[5], r[6], r[7]);
  };

  const int lane = t & 63, wv = t >> 6, rl = lane & 15, gh = lane >> 4;
  f32x4 acc00 = {0.f, 0.f, 0.f, 0.f}, acc01 = acc00, acc10 = acc00, acc11 = acc00;

  auto COMP = [&](const ushort* buf, int k) {
    const ushort* aP = wt + (size_t)(wv * 32 + rl) * KC + k * 128 + gh * 8;
    __builtin_amdgcn_s_setprio(1);
#pragma unroll
    for (int kk = 0; kk < 4; ++kk) {
      short8 av0 = *(const short8*)(aP + kk * 32);
      short8 av1 = *(const short8*)(aP + (size_t)16 * KC + kk * 32);
      short8 bv0 = *(const short8*)(buf + swz16(rl, kk * 64 + gh * 16));
      short8 bv1 = *(const short8*)(buf + swz16(16 + rl, kk * 64 + gh * 16));
      acc00 = __builtin_amdgcn_mfma_f32_16x16x32_bf16(av0, bv0, acc00, 0, 0, 0);
      acc01 = __builtin_amdgcn_mfma_f32_16x16x32_bf16(av0, bv1, acc01, 0, 0, 0);
      acc10 = __builtin_amdgcn_mfma_f32_16x16x32_bf16(av1, bv0, acc10, 0, 0, 0);
      acc11 = __builtin_amdgcn_mfma_f32_16x16x32_bf16(av1, bv1, acc11, 0, 0, 0);
    }
    __builtin_amdgcn_s_setprio(0);
  };

  SLOAD(0);
  asm volatile("s_waitcnt vmcnt(0)" ::: "memory");
  __builtin_amdgcn_sched_barrier(0);
  SWRITE(s_buf[0]);
  __syncthreads();
  for (int k = 0; k < 9; ++k) {
    if (k < 8) SLOAD(k + 1);
    COMP(s_buf[k & 1], k);
    __builtin_amdgcn_sched_barrier(0);
    if (k < 8) {
      asm volatile("s_waitcnt vmcnt(0)" ::: "memory");
      __builtin_amdgcn_sched_barrier(0);
      SWRITE(s_buf[(k + 1) & 1]);
      __syncthreads();
    }
  }

  // C-write + fused BN partial sums -> per-block slots (NO atomics; round-6's
  // 400K contended atomicAdds onto 16 cache lines cost ~290us — Guideline 12)
  float* outb = outr + (size_t)b * O * HW + hw0 + rl;
  const int nb = blockIdx.x;
#pragma unroll
  for (int mi = 0; mi < 2; ++mi) {
    f32x4 a0 = mi ? acc10 : acc00;
    f32x4 a1 = mi ? acc11 : acc01;
#pragma unroll
    for (int r = 0; r < 4; ++r) {
      int o = wv * 32 + mi * 16 + gh * 4 + r;
      outb[(size_t)o * HW] = a0[r];
      outb[(size_t)o * HW + 16] = a1[r];
      float s = a0[r] + a1[r];
      float s2 = fmaf(a0[r], a0[r], a1[r] * a1[r]);
#pragma unroll
      for (int m = 1; m < 16; m <<= 1) {
        s += __shfl_xor(s, m);
        s2 += __shfl_xor(s2, m);
      }
      if (rl == 0) {
        part2[(size_t)(2 * o) * NBLK + nb] = s;
        part2[(size_t)(2 * o + 1) * NBLK + nb] = s2;
      }
    }
  }
}

// ------- kernel 3: reduce per-block partials -> stats[256] ------------------
__global__ __launch_bounds__(256) void k_bnred(const float* __restrict__ part2,
                                               float* __restrict__ stats) {
  const int j = blockIdx.x;          // 0..255 = 2*o + stat
  float s = 0.f;
  for (int i = threadIdx.x; i < NBLK; i += 256) s += part2[(size_t)j * NBLK + i];
#pragma unroll
  for (int off = 32; off > 0; off >>= 1) s += __shfl_down(s, off);
  __shared__ float rs[4];
  int wid = threadIdx.x >> 6, lane = threadIdx.x & 63;
  if (lane == 0) rs[wid] = s;
  __syncthreads();
  if (threadIdx.x == 0) stats[j] = rs[0] + rs[1] + rs[2] + rs[3];
}

// ------- kernel 4: BN finalize + affine + SiLU, in place on d_out -----------
__global__ __launch_bounds__(256) void k_bnapply2(
    float* __restrict__ outr, const float* __restrict__ stats,
    const float* __restrict__ gamma, const float* __restrict__ beta) {
  const int n4 = B * O * HW / 4;
  for (int i = blockIdx.x * blockDim.x + threadIdx.x; i < n4;
       i += gridDim.x * blockDim.x) {
    int o = (i / (HW / 4)) % O;
    float S = stats[2 * o], S2 = stats[2 * o + 1];
    const float inv = 1.0f / (float)(B * HW);
    float mu = S * inv;
    float rstd = rsqrtf(fmaf(S2, inv, -mu * mu) + 1e-5f);
    float a = rstd * gamma[o];
    float bb = fmaf(-mu, a, beta[o]);
    float4 v = ((const float4*)outr)[i];
    float y0 = fmaf(v.x, a, bb);
    float y1 = fmaf(v.y, a, bb);
    float y2 = fmaf(v.z, a, bb);
    float y3 = fmaf(v.w, a, bb);
    v.x = y0 / (1.0f + __expf(-y0));
    v.y = y1 / (1.0f + __expf(-y1));
    v.z = y2 / (1.0f + __expf(-y2));
    v.w = y3 / (1.0f + __expf(-y3));
    ((float4*)outr)[i] = v;
  }
}

extern "C" void kernel_launch(void* const* d_in, const int* in_sizes, int n_in,
                              void* d_out, int out_size, void* d_ws, size_t ws_size,
                              hipStream_t stream) {
  const float* x = (const float*)d_in[0];
  const float* w_dcn = (const float*)d_in[1];
  // d_in[2] = b_dcn: per-channel constant, exactly cancelled by BN mean-sub.
  const float* w_off = (const float*)d_in[3];
  const float* b_off = (const float*)d_in[4];
  const float* gamma = (const float*)d_in[5];
  const float* beta = (const float*)d_in[6];
  float* out = (float*)d_out;
  // ws: om 5.53MB | xt 13.1MB | wt 288KB | wof 72KB | part2 1.64MB | stats | zrow
  float* om = (float*)d_ws;
  ushort* xt = (ushort*)(om + (size_t)B * 27 * HW);
  ushort* wt = xt + (size_t)B * HW * C;
  ushort* wof = wt + (size_t)O * KC;
  float* part2 = (float*)(wof + (size_t)32 * KC);
  float* stats = part2 + (size_t)256 * NBLK;
  ushort* zrow = (ushort*)(stats + 256);

  k_xt<<<NPIX / 16, 256, 0, stream>>>(x, xt);
  k_wt2<<<(O * KC + 255) / 256, 256, 0, stream>>>(w_dcn, w_off, wt, wof, zrow);
  k_offc4<<<NPIX / PX, 256, 0, stream>>>(xt, wof, zrow, b_off, om);
  k_dcn3<<<NPIX / PX, 256, 0, stream>>>(xt, om, wt, out, part2);
  k_bnred<<<256, 256, 0, stream>>>(part2, stats);
  k_bnapply2<<<2048, 256, 0, stream>>>(out, stats, gamma, beta);
}

// Round 8
// 230.538 us; speedup vs baseline: 2.2301x; 1.0641x over previous
//
#include <hip/hip_runtime.h>
#include <hip/hip_bf16.h>
#include <hip/hip_fp16.h>

constexpr int B = 8, C = 128, H = 80, W = 80, O = 128;
constexpr int HW = H * W;              // 6400
constexpr int NPIX = B * HW;           // 51200
constexpr int KC = C * 9;              // 1152
constexpr int DPX = 64;                // pixels per block (dcn kernel)
constexpr int NBLK = NPIX / DPX;       // 800

typedef _Float16 h8 __attribute__((ext_vector_type(8)));
typedef _Float16 h2 __attribute__((ext_vector_type(2)));
typedef float f32x4 __attribute__((ext_vector_type(4)));

__device__ inline h8 as_h8(uint4 v) { h8 r; __builtin_memcpy(&r, &v, 16); return r; }
__device__ inline h2 u2h(uint u) { h2 r; __builtin_memcpy(&r, &u, 4); return r; }
__device__ inline uint h2u(h2 h) { uint r; __builtin_memcpy(&r, &h, 4); return r; }
__device__ inline uint pkh(float a, float b) {
  h2 h = { (_Float16)a, (_Float16)b };
  return h2u(h);
}
// ushort index into a [row][256B] LDS buffer, XOR-swizzled (involution).
__device__ inline int swz16(int row, int byte) {
  return (row * 256 + (byte ^ ((row & 7) << 4))) >> 1;
}

// ------- kernel 0a: x [B][C][HW] fp32 -> xt [B][HW][C] fp16 (LDS transpose) -
__global__ __launch_bounds__(256) void k_xt(const float* __restrict__ x,
                                            _Float16* __restrict__ xt) {
  __shared__ uint tile32[64 * 64];   // [hw][c-pair], swizzled rows (16KB)
  const int t = threadIdx.x;
  const int p0 = blockIdx.x * 64;
  const int b = p0 / HW, hw0 = p0 - b * HW;
  const int w = t >> 6, l = t & 63;
  // phase R: coalesced 256B row reads, packed fp16 pair into LDS
#pragma unroll
  for (int j = 0; j < 16; ++j) {
    int c0 = (j * 4 + w) * 2;
    float f0 = x[((size_t)(b * C + c0)) * HW + hw0 + l];
    float f1 = x[((size_t)(b * C + c0 + 1)) * HW + hw0 + l];
    int byte = l * 256 + ((c0 * 2) ^ ((l & 7) << 4));
    tile32[byte >> 2] = pkh(f0, f1);
  }
  __syncthreads();
  // phase W: conflict-free swizzled b128 reads, fully coalesced 16B stores
  _Float16* dst = xt + (size_t)(b * HW + hw0) * C;
#pragma unroll
  for (int it = 0; it < 4; ++it) {
    int g = w * 4096 + it * 1024 + l * 16;
    int row = g >> 8, inner = g & 255;
    uint4 v = *(const uint4*)((const char*)tile32 + row * 256 + (inner ^ ((row & 7) << 4)));
    *(uint4*)(dst + (g >> 1)) = v;
  }
}

// ------- kernel 0b: weight transforms, k-major fp16; zero zrow --------------
__global__ __launch_bounds__(256) void k_wt2(const float* __restrict__ w_dcn,
                                             const float* __restrict__ w_off,
                                             _Float16* __restrict__ wt,
                                             _Float16* __restrict__ wof,
                                             _Float16* __restrict__ zrow) {
  int i = blockIdx.x * 256 + threadIdx.x;
  if (i < O * KC) {
    int c = i & 127, k = (i >> 7) % 9, o = i / KC;
    wt[i] = (_Float16)w_dcn[(size_t)o * KC + c * 9 + k];
  }
  if (i < 32 * KC) {
    int c = i & 127, k = (i >> 7) % 9, o = i / KC;
    wof[i] = (o < 27) ? (_Float16)w_off[((size_t)o * C + c) * 9 + k] : (_Float16)0.f;
  }
  if (i < 128) zrow[i] = (_Float16)0.f;
}

// ------- kernel 1: offset conv via MFMA, NO LDS (B read direct from L2) -----
__global__ __launch_bounds__(256, 6) void k_offc4(
    const _Float16* __restrict__ xt, const _Float16* __restrict__ wof,
    const _Float16* __restrict__ zrow, const float* __restrict__ b_off,
    float* __restrict__ om) {
  const int t = threadIdx.x;
  const int bid = (blockIdx.x & 7) * 200 + (blockIdx.x >> 3);  // XCD chunking
  const int b = bid / 200, hw0 = (bid - b * 200) * 32;
  const int lane = t & 63, wv = t >> 6, rl = lane & 15, gh = lane >> 4;
  const int mi = wv & 1, nt = wv >> 1;
  const int px = hw0 + nt * 16 + rl;
  const int hp = px / W, wp = px - hp * W;
  const _Float16* xb = xt + (size_t)b * HW * C;
  f32x4 acc = {0.f, 0.f, 0.f, 0.f};
#pragma unroll
  for (int k = 0; k < 9; ++k) {
    int ky = k / 3, kx = k - ky * 3;
    int y = hp + ky - 1, xx = wp + kx - 1;
    bool ok = ((unsigned)y < (unsigned)H) && ((unsigned)xx < (unsigned)W);
    const _Float16* rowp = ok ? (xb + (size_t)(y * W + xx) * C) : zrow;
    const _Float16* aP = wof + (size_t)(mi * 16 + rl) * KC + k * 128 + gh * 8;
#pragma unroll
    for (int kk = 0; kk < 4; ++kk) {
      h8 av = *(const h8*)(aP + kk * 32);
      h8 bv = *(const h8*)(rowp + kk * 32 + gh * 8);
      acc = __builtin_amdgcn_mfma_f32_16x16x32_f16(av, bv, acc, 0, 0, 0);
    }
  }
  float* ob = om + (size_t)b * 27 * HW + hw0 + nt * 16 + rl;
#pragma unroll
  for (int r = 0; r < 4; ++r) {
    int oc = mi * 16 + gh * 4 + r;
    if (oc < 27) ob[(size_t)oc * HW] = acc[r] + b_off[oc];
  }
}

// ------- kernel 2: gather + MFMA GEMM, all-asm loads + counted vmcnt --------
// 256 thr = 4 waves, 64 px/block, all O=128. Wave: 2 m-tiles x 4 n-tiles.
__global__ __launch_bounds__(256, 3) void k_dcn4(
    const _Float16* __restrict__ xt, const float* __restrict__ om,
    const _Float16* __restrict__ wt, float* __restrict__ outr,
    float* __restrict__ part2) {
  __shared__ float s_w[DPX][9][4];
  __shared__ int s_i[DPX][9][4];
  __shared__ __align__(16) ushort s_buf[2][DPX * 128];
  const int t = threadIdx.x;
  const int bid = (blockIdx.x & 7) * 100 + (blockIdx.x >> 3);  // XCD chunking
  const int b = bid / 100, hw0 = (bid - b * 100) * DPX;

  // metadata: 64 px x 9 taps (mask folded into corner weights)
  for (int idx = t; idx < DPX * 9; idx += 256) {
    int px = idx / 9, k = idx - (idx / 9) * 9;
    int hw = hw0 + px, h = hw / W, w = hw - (hw / W) * W;
    int ky = k / 3, kx = k - ky * 3;
    const float* omp = om + (size_t)b * 27 * HW + hw;
    float dy = omp[(size_t)(2 * k) * HW];
    float dx = omp[(size_t)(2 * k + 1) * HW];
    float mk = 1.0f / (1.0f + __expf(-omp[(size_t)(18 + k) * HW]));
    float py = dy + (float)(h - 1 + ky);
    float pxf = dx + (float)(w - 1 + kx);
    float y0f = floorf(py), x0f = floorf(pxf);
    float wy1 = py - y0f, wx1 = pxf - x0f;
    float wy0 = 1.0f - wy1, wx0 = 1.0f - wx1;
    int y0 = (int)y0f, x0 = (int)x0f;
    int y1 = y0 + 1, x1 = x0 + 1;
    bool vy0 = (y0 >= 0) && (y0 < H);
    bool vy1 = (y1 >= 0) && (y1 < H);
    bool vx0 = (x0 >= 0) && (x0 < W);
    bool vx1 = (x1 >= 0) && (x1 < W);
    int cy0 = min(max(y0, 0), H - 1), cy1 = min(max(y1, 0), H - 1);
    int cx0 = min(max(x0, 0), W - 1), cx1 = min(max(x1, 0), W - 1);
    s_w[px][k][0] = (vy0 && vx0) ? wy0 * wx0 * mk : 0.0f;
    s_w[px][k][1] = (vy0 && vx1) ? wy0 * wx1 * mk : 0.0f;
    s_w[px][k][2] = (vy1 && vx0) ? wy1 * wx0 * mk : 0.0f;
    s_w[px][k][3] = (vy1 && vx1) ? wy1 * wx1 * mk : 0.0f;
    s_i[px][k][0] = cy0 * W + cx0;
    s_i[px][k][1] = cy0 * W + cx1;
    s_i[px][k][2] = cy1 * W + cx0;
    s_i[px][k][3] = cy1 * W + cx1;
  }
  __syncthreads();

  const int sp = t >> 2, sq = t & 3;          // staging: pixel, 64B chunk
  const _Float16* xbq = xt + (size_t)b * HW * C + sq * 32;
  const int lane = t & 63, wv = t >> 6, rl = lane & 15, gh = lane >> 4;
  const _Float16* wbase = wt + (size_t)(wv * 32 + rl) * KC + gh * 8;

  // pinned prefetch: 16 gather + 8 weight uint4 (96 VGPR)
  uint4 gA0, gA1, gA2, gA3, gB0, gB1, gB2, gB3;
  uint4 gC0, gC1, gC2, gC3, gD0, gD1, gD2, gD3;
  uint4 wA0, wA1, wA2, wA3, wB0, wB1, wB2, wB3;
  float cw0, cw1, cw2, cw3;

#define GL4(o0, o1, o2, o3, P)                                            \
  asm volatile("global_load_dwordx4 %0, %4, off\n\t"                      \
               "global_load_dwordx4 %1, %4, off offset:16\n\t"            \
               "global_load_dwordx4 %2, %4, off offset:32\n\t"            \
               "global_load_dwordx4 %3, %4, off offset:48"                \
               : "=&v"(o0), "=&v"(o1), "=&v"(o2), "=&v"(o3) : "v"(P))
#define WL4(o0, o1, o2, o3, P)                                            \
  asm volatile("global_load_dwordx4 %0, %4, off\n\t"                      \
               "global_load_dwordx4 %1, %4, off offset:64\n\t"            \
               "global_load_dwordx4 %2, %4, off offset:128\n\t"           \
               "global_load_dwordx4 %3, %4, off offset:192"               \
               : "=&v"(o0), "=&v"(o1), "=&v"(o2), "=&v"(o3) : "v"(P))

  auto GLOAD = [&](int k) {   // issue 16 gather loads for tap k
    int4 ii = *(const int4*)&s_i[sp][k][0];
    float4 wf = *(const float4*)&s_w[sp][k][0];
    cw0 = wf.x; cw1 = wf.y; cw2 = wf.z; cw3 = wf.w;
    GL4(gA0, gA1, gA2, gA3, xbq + (size_t)ii.x * C);
    GL4(gB0, gB1, gB2, gB3, xbq + (size_t)ii.y * C);
    GL4(gC0, gC1, gC2, gC3, xbq + (size_t)ii.z * C);
    GL4(gD0, gD1, gD2, gD3, xbq + (size_t)ii.w * C);
  };
  auto WLOAD = [&](int k) {   // issue 8 weight loads for tap k
    const _Float16* a0 = wbase + k * 128;
    WL4(wA0, wA1, wA2, wA3, a0);
    WL4(wB0, wB1, wB2, wB3, a0 + 16 * KC);
  };

  auto SWRITE = [&](ushort* buf) {
    uint qa[16] = {gA0.x, gA0.y, gA0.z, gA0.w, gA1.x, gA1.y, gA1.z, gA1.w,
                   gA2.x, gA2.y, gA2.z, gA2.w, gA3.x, gA3.y, gA3.z, gA3.w};
    uint qb[16] = {gB0.x, gB0.y, gB0.z, gB0.w, gB1.x, gB1.y, gB1.z, gB1.w,
                   gB2.x, gB2.y, gB2.z, gB2.w, gB3.x, gB3.y, gB3.z, gB3.w};
    uint qc[16] = {gC0.x, gC0.y, gC0.z, gC0.w, gC1.x, gC1.y, gC1.z, gC1.w,
                   gC2.x, gC2.y, gC2.z, gC2.w, gC3.x, gC3.y, gC3.z, gC3.w};
    uint qd[16] = {gD0.x, gD0.y, gD0.z, gD0.w, gD1.x, gD1.y, gD1.z, gD1.w,
                   gD2.x, gD2.y, gD2.z, gD2.w, gD3.x, gD3.y, gD3.z, gD3.w};
    h2 W0 = {(_Float16)cw0, (_Float16)cw0};
    h2 W1 = {(_Float16)cw1, (_Float16)cw1};
    h2 W2 = {(_Float16)cw2, (_Float16)cw2};
    h2 W3 = {(_Float16)cw3, (_Float16)cw3};
    uint r[16];
#pragma unroll
    for (int d = 0; d < 16; ++d) {
      h2 o = u2h(qa[d]) * W0 + u2h(qb[d]) * W1 + u2h(qc[d]) * W2 + u2h(qd[d]) * W3;
      r[d] = h2u(o);
    }
#pragma unroll
    for (int e = 0; e < 4; ++e)
      *(uint4*)(buf + swz16(sp, sq * 64 + e * 16)) =
          make_uint4(r[4 * e], r[4 * e + 1], r[4 * e + 2], r[4 * e + 3]);
  };

  f32x4 acc[2][4];
#pragma unroll
  for (int m = 0; m < 2; ++m)
#pragma unroll
    for (int nt = 0; nt < 4; ++nt) acc[m][nt] = {0.f, 0.f, 0.f, 0.f};

  auto COMP = [&](const ushort* buf) {   // pure LDS + MFMA (no global loads)
    h8 av0, av1, bv;
#define KSTEP(WA, WB, KB)                                                  \
  av0 = as_h8(WA); av1 = as_h8(WB);                                        \
  _Pragma("unroll")                                                        \
  for (int nt = 0; nt < 4; ++nt) {                                         \
    bv = *(const h8*)(buf + swz16(nt * 16 + rl, KB + gh * 16));            \
    acc[0][nt] = __builtin_amdgcn_mfma_f32_16x16x32_f16(av0, bv, acc[0][nt], 0, 0, 0); \
    acc[1][nt] = __builtin_amdgcn_mfma_f32_16x16x32_f16(av1, bv, acc[1][nt], 0, 0, 0); \
  }
    KSTEP(wA0, wB0, 0)
    KSTEP(wA1, wB1, 64)
    KSTEP(wA2, wB2, 128)
    KSTEP(wA3, wB3, 192)
#undef KSTEP
  };

  // prologue: tap 0 in flight
  GLOAD(0); WLOAD(0);
  asm volatile("s_waitcnt vmcnt(8)" ::: "memory");   // gather(0) done
  __builtin_amdgcn_sched_barrier(0);
  SWRITE(s_buf[0]);
  __syncthreads();

  for (int k = 0; k < 9; ++k) {
    if (k < 8) GLOAD(k + 1);                          // +16 in flight
    if (k < 8) asm volatile("s_waitcnt vmcnt(16)" ::: "memory");  // wt(k) done
    else       asm volatile("s_waitcnt vmcnt(0)" ::: "memory");
    __builtin_amdgcn_sched_barrier(0);
    COMP(s_buf[k & 1]);
    if (k < 8) {
      WLOAD(k + 1);                                   // +8 in flight
      asm volatile("s_waitcnt vmcnt(8)" ::: "memory"); // gather(k+1) done
      __builtin_amdgcn_sched_barrier(0);
      SWRITE(s_buf[(k + 1) & 1]);
      __syncthreads();
    }
  }
#undef GL4
#undef WL4

  // C-write + fused BN partial sums -> per-block slots (no atomics)
  float* outb = outr + (size_t)b * O * HW + hw0 + rl;
  const int nb = blockIdx.x;
#pragma unroll
  for (int mi = 0; mi < 2; ++mi)
#pragma unroll
    for (int r = 0; r < 4; ++r) {
      int o = wv * 32 + mi * 16 + gh * 4 + r;
      float s = 0.f, s2 = 0.f;
#pragma unroll
      for (int nt = 0; nt < 4; ++nt) {
        float v = acc[mi][nt][r];
        outb[(size_t)o * HW + nt * 16] = v;
        s += v;
        s2 = fmaf(v, v, s2);
      }
#pragma unroll
      for (int m = 1; m < 16; m <<= 1) {
        s += __shfl_xor(s, m);
        s2 += __shfl_xor(s2, m);
      }
      if (rl == 0) {
        part2[(size_t)(2 * o) * NBLK + nb] = s;
        part2[(size_t)(2 * o + 1) * NBLK + nb] = s2;
      }
    }
}

// ------- kernel 3: reduce per-block partials -> stats[256] ------------------
__global__ __launch_bounds__(256) void k_bnred(const float* __restrict__ part2,
                                               float* __restrict__ stats) {
  const int j = blockIdx.x;          // 0..255 = 2*o + stat
  float s = 0.f;
  for (int i = threadIdx.x; i < NBLK; i += 256) s += part2[(size_t)j * NBLK + i];
#pragma unroll
  for (int off = 32; off > 0; off >>= 1) s += __shfl_down(s, off);
  __shared__ float rs[4];
  int wid = threadIdx.x >> 6, lane = threadIdx.x & 63;
  if (lane == 0) rs[wid] = s;
  __syncthreads();
  if (threadIdx.x == 0) stats[j] = rs[0] + rs[1] + rs[2] + rs[3];
}

// ------- kernel 4: BN finalize + affine + SiLU, in place on d_out -----------
__global__ __launch_bounds__(256) void k_bnapply2(
    float* __restrict__ outr, const float* __restrict__ stats,
    const float* __restrict__ gamma, const float* __restrict__ beta) {
  const int n4 = B * O * HW / 4;
  for (int i = blockIdx.x * blockDim.x + threadIdx.x; i < n4;
       i += gridDim.x * blockDim.x) {
    int o = (i / (HW / 4)) % O;
    float S = stats[2 * o], S2 = stats[2 * o + 1];
    const float inv = 1.0f / (float)(B * HW);
    float mu = S * inv;
    float rstd = rsqrtf(fmaf(S2, inv, -mu * mu) + 1e-5f);
    float a = rstd * gamma[o];
    float bb = fmaf(-mu, a, beta[o]);
    float4 v = ((const float4*)outr)[i];
    float y0 = fmaf(v.x, a, bb);
    float y1 = fmaf(v.y, a, bb);
    float y2 = fmaf(v.z, a, bb);
    float y3 = fmaf(v.w, a, bb);
    v.x = y0 / (1.0f + __expf(-y0));
    v.y = y1 / (1.0f + __expf(-y1));
    v.z = y2 / (1.0f + __expf(-y2));
    v.w = y3 / (1.0f + __expf(-y3));
    ((float4*)outr)[i] = v;
  }
}

extern "C" void kernel_launch(void* const* d_in, const int* in_sizes, int n_in,
                              void* d_out, int out_size, void* d_ws, size_t ws_size,
                              hipStream_t stream) {
  const float* x = (const float*)d_in[0];
  const float* w_dcn = (const float*)d_in[1];
  // d_in[2] = b_dcn: per-channel constant, exactly cancelled by BN mean-sub.
  const float* w_off = (const float*)d_in[3];
  const float* b_off = (const float*)d_in[4];
  const float* gamma = (const float*)d_in[5];
  const float* beta = (const float*)d_in[6];
  float* out = (float*)d_out;
  // ws: om 5.53MB | xt 13.1MB | wt 288KB | wof 72KB | part2 800KB | stats | zrow
  float* om = (float*)d_ws;
  _Float16* xt = (_Float16*)(om + (size_t)B * 27 * HW);
  _Float16* wt = xt + (size_t)B * HW * C;
  _Float16* wof = wt + (size_t)O * KC;
  float* part2 = (float*)(wof + (size_t)32 * KC);
  float* stats = part2 + (size_t)256 * NBLK;
  _Float16* zrow = (_Float16*)(stats + 256);

  k_xt<<<NPIX / 64, 256, 0, stream>>>(x, xt);
  k_wt2<<<(O * KC + 255) / 256, 256, 0, stream>>>(w_dcn, w_off, wt, wof, zrow);
  k_offc4<<<NPIX / 32, 256, 0, stream>>>(xt, wof, zrow, b_off, om);
  k_dcn4<<<NPIX / DPX, 256, 0, stream>>>(xt, om, wt, out, part2);
  k_bnred<<<256, 256, 0, stream>>>(part2, stats);
  k_bnapply2<<<2048, 256, 0, stream>>>(out, stats, gamma, beta);
}